// Round 5
// baseline (636.581 us; speedup 1.0000x reference)
//
#include <hip/hip_runtime.h>
#include <hip/hip_bf16.h>
#include <math.h>

typedef __bf16 bf16_t;
typedef __bf16 bf16x8 __attribute__((ext_vector_type(8)));
typedef float floatx4 __attribute__((ext_vector_type(4)));
typedef unsigned short ushort4v __attribute__((ext_vector_type(4)));

#define AS1 __attribute__((address_space(1)))
#define AS3 __attribute__((address_space(3)))

// Problem constants
#define BB 4
#define SS 2048
#define DD 1024
#define HH 16
#define DH 64
#define MM (BB * SS)          // 8192

__device__ __forceinline__ void gld_lds16(const bf16_t* g, bf16_t* l) {
    __builtin_amdgcn_global_load_lds((const AS1 void*)g, (AS3 void*)l, 16, 0, 0);
}

// ---------------------------------------------------------------------------
// dtype detector: fp32 data's even halfwords are uniform bits -> many with
// bf16-exponent-field >= 144. bf16 N(0,1) never exceeds ~130. flag=1 -> fp32.
// ---------------------------------------------------------------------------
__global__ void detect_dtype(const unsigned short* __restrict__ x, int* __restrict__ flag) {
    if (threadIdx.x == 0) {
        int hits = 0;
        for (int i = 0; i < 128; ++i) {
            int e = (x[i] >> 7) & 0xFF;
            if (e >= 144) ++hits;
        }
        *flag = (hits >= 4) ? 1 : 0;
    }
}

// ---------------------------------------------------------------------------
// n-element convert (fp32->bf16) or copy (bf16->bf16), 4 elems/thread
// ---------------------------------------------------------------------------
__global__ __launch_bounds__(256)
void convert_x(const void* __restrict__ in, bf16_t* __restrict__ out,
               const int* __restrict__ flag, int n) {
    const int i4 = (blockIdx.x * 256 + threadIdx.x) * 4;
    if (i4 >= n) return;
    if (*flag) {
        floatx4 v = ((const floatx4*)in)[i4 >> 2];
        out[i4 + 0] = (bf16_t)v[0];
        out[i4 + 1] = (bf16_t)v[1];
        out[i4 + 2] = (bf16_t)v[2];
        out[i4 + 3] = (bf16_t)v[3];
    } else {
        ((ushort4v*)out)[i4 >> 2] = ((const ushort4v*)in)[i4 >> 2];
    }
}

__global__ void convert1d(const void* __restrict__ in, bf16_t* __restrict__ out,
                          const int* __restrict__ flag, int n) {
    const int i = blockIdx.x * 256 + threadIdx.x;
    if (i >= n) return;
    out[i] = (*flag) ? (bf16_t)((const float*)in)[i] : ((const bf16_t*)in)[i];
}

// ---------------------------------------------------------------------------
// Tiled transpose + convert: in[R][C] (fp32 or bf16 per flag) -> out[C][R] bf16
// ---------------------------------------------------------------------------
__global__ void transpose_cvt(const void* __restrict__ in, bf16_t* __restrict__ out,
                              const int* __restrict__ flag, int R, int C) {
    __shared__ bf16_t tile[32][33];
    const int tx = threadIdx.x & 31;
    const int ty = threadIdx.x >> 5;          // 0..7
    const int r0 = blockIdx.y * 32;
    const int c0 = blockIdx.x * 32;
    if (*flag) {
        const float* fin = (const float*)in;
#pragma unroll
        for (int i = 0; i < 32; i += 8)
            tile[ty + i][tx] = (bf16_t)fin[(size_t)(r0 + ty + i) * C + (c0 + tx)];
    } else {
        const bf16_t* bin = (const bf16_t*)in;
#pragma unroll
        for (int i = 0; i < 32; i += 8)
            tile[ty + i][tx] = bin[(size_t)(r0 + ty + i) * C + (c0 + tx)];
    }
    __syncthreads();
#pragma unroll
    for (int i = 0; i < 32; i += 8)
        out[(size_t)(c0 + ty + i) * R + (r0 + tx)] = tile[tx][ty + i];
}

// ---------------------------------------------------------------------------
// 128x128 bf16 MFMA GEMM, A[M,K] row-major, Bt[N,K] row-major (B transposed).
// MODE 0: qkv epilogue — q -> bf16 scatter [B,H,S,dh] (scratch for flash);
//         k,v -> FP32 scatter [B,H,S,dh] (final outputs).
// MODE 1: plain fp32 out: outf[m*N + n].
// grid: (N/128, M/128), 256 threads.  (m97 structure, DMA staging)
// ---------------------------------------------------------------------------
template <int MODE>
__global__ __launch_bounds__(256)
void gemm128(const bf16_t* __restrict__ A, const bf16_t* __restrict__ Bt,
             const bf16_t* __restrict__ bias,
             bf16_t* __restrict__ qout, float* __restrict__ kf, float* __restrict__ vf,
             float* __restrict__ outf,
             int K, int N) {
    __shared__ bf16_t As[128 * 32];
    __shared__ bf16_t Bs[128 * 32];
    const int tid = threadIdx.x;
    const int wave = tid >> 6;
    const int lane = tid & 63;
    const int quad = lane >> 4;
    const int l16 = lane & 15;
    const int m0 = blockIdx.y * 128;
    const int n0 = blockIdx.x * 128;
    const int wm = (wave & 1) * 64;
    const int wn = (wave >> 1) * 64;

    floatx4 acc[4][4];
#pragma unroll
    for (int i = 0; i < 4; ++i)
#pragma unroll
        for (int j = 0; j < 4; ++j) {
            floatx4 z = {0.f, 0.f, 0.f, 0.f};
            acc[i][j] = z;
        }

    const int srow = wave * 32 + (lane >> 2);
    const int scol = (lane & 3) * 8;
    const bf16_t* ag = A + (size_t)(m0 + srow) * K + scol;
    const bf16_t* bg = Bt + (size_t)(n0 + srow) * K + scol;
    bf16_t* al = As + (wave * 32) * 32;   // wave-uniform base (DMA adds lane*16B)
    bf16_t* bl = Bs + (wave * 32) * 32;

    for (int k0 = 0; k0 < K; k0 += 32) {
        gld_lds16(ag + k0, al);
        gld_lds16(ag + (size_t)16 * K + k0, al + 16 * 32);
        gld_lds16(bg + k0, bl);
        gld_lds16(bg + (size_t)16 * K + k0, bl + 16 * 32);
        __syncthreads();

        bf16x8 af[4], bfv[4];
#pragma unroll
        for (int mt = 0; mt < 4; ++mt)
            af[mt] = *(const bf16x8*)&As[(wm + mt * 16 + l16) * 32 + quad * 8];
#pragma unroll
        for (int nt = 0; nt < 4; ++nt)
            bfv[nt] = *(const bf16x8*)&Bs[(wn + nt * 16 + l16) * 32 + quad * 8];
#pragma unroll
        for (int mt = 0; mt < 4; ++mt)
#pragma unroll
            for (int nt = 0; nt < 4; ++nt)
                acc[mt][nt] = __builtin_amdgcn_mfma_f32_16x16x32_bf16(
                    af[mt], bfv[nt], acc[mt][nt], 0, 0, 0);
        __syncthreads();
    }

    // C row = wm+mt*16+quad*4+r, col = wn+nt*16+l16
#pragma unroll
    for (int mt = 0; mt < 4; ++mt) {
#pragma unroll
        for (int nt = 0; nt < 4; ++nt) {
            const int nc = n0 + wn + nt * 16 + l16;
            const float bv = (float)bias[nc];
            if (MODE == 0) {
                const int sec = nc >> 10;       // 0=q 1=k 2=v
                const int c = nc & 1023;
                const int h = c >> 6;
                const int dcol = c & 63;
#pragma unroll
                for (int r = 0; r < 4; ++r) {
                    const int m = m0 + wm + mt * 16 + quad * 4 + r;
                    const int b = m >> 11;
                    const int s = m & 2047;
                    const size_t di = ((size_t)(b * HH + h) * SS + s) * DH + dcol;
                    const float val = acc[mt][nt][r] + bv;
                    if (sec == 0)      qout[di] = (bf16_t)val;
                    else if (sec == 1) kf[di] = val;
                    else               vf[di] = val;
                }
            } else {
#pragma unroll
                for (int r = 0; r < 4; ++r) {
                    const int m = m0 + wm + mt * 16 + quad * 4 + r;
                    outf[(size_t)m * N + nc] = acc[mt][nt][r] + bv;
                }
            }
        }
    }
}

// ---------------------------------------------------------------------------
// Causal flash attention. q: [B*H,S,64] bf16.  k,v: [B*H,S,64] FP32 (the
// final output sections).  ao: [B,S,1024] bf16.
// Block = 64 q-rows (4 waves x 16), key tiles of 32. grid (S/64, B*H), 256t.
// ---------------------------------------------------------------------------
__global__ __launch_bounds__(256)
void flash64(const bf16_t* __restrict__ q, const float* __restrict__ k,
             const float* __restrict__ v, bf16_t* __restrict__ ao) {
    __shared__ bf16_t Ks[2][32 * 32];   // [dchunk][key][32]
    __shared__ bf16_t Vt[64 * 32];      // [d][key]
    __shared__ bf16_t Ps[4][16 * 32];   // per-wave P tile [qrow][key]

    const int tid = threadIdx.x;
    const int wave = tid >> 6;
    const int lane = tid & 63;
    const int quad = lane >> 4;
    const int l16 = lane & 15;
    const int t0 = blockIdx.x * 64;
    const int bh = blockIdx.y;
    const int b = bh >> 4;
    const int h = bh & 15;
    const bf16_t* qp = q + (size_t)bh * SS * DH;
    const float* kp = k + (size_t)bh * SS * DH;
    const float* vp = v + (size_t)bh * SS * DH;

    // Q fragments (A-layout: A[m=l16][k=quad*8+j])
    bf16x8 aq0, aq1;
    {
        const bf16_t* qr = qp + (size_t)(t0 + wave * 16 + l16) * DH + quad * 8;
        aq0 = *(const bf16x8*)qr;         // d 0..31
        aq1 = *(const bf16x8*)(qr + 32);  // d 32..63
    }

    floatx4 o[4];
#pragma unroll
    for (int nt = 0; nt < 4; ++nt) {
        floatx4 z = {0.f, 0.f, 0.f, 0.f};
        o[nt] = z;
    }
    float mrow[4], lrow[4];
#pragma unroll
    for (int r = 0; r < 4; ++r) { mrow[r] = -1e30f; lrow[r] = 0.f; }

    const float c2 = 0.18033688011112042f;   // (1/sqrt(64)) * log2(e)

    // staging: thread -> key tid&31, 8-d group tid>>5
    const int skey = tid & 31;
    const int sdg = tid >> 5;               // 0..7

    const int qimax = t0 + wave * 16 + 15;

    for (int j0 = 0; j0 < t0 + 64; j0 += 32) {
        {
            const float* kr = kp + (size_t)(j0 + skey) * DH + sdg * 8;
            floatx4 k0 = *(const floatx4*)kr;
            floatx4 k1 = *(const floatx4*)(kr + 4);
            bf16x8 kb;
#pragma unroll
            for (int i = 0; i < 4; ++i) { kb[i] = (bf16_t)k0[i]; kb[4 + i] = (bf16_t)k1[i]; }
            *(bf16x8*)&Ks[sdg >> 2][skey * 32 + (sdg & 3) * 8] = kb;

            const float* vr = vp + (size_t)(j0 + skey) * DH + sdg * 8;
            floatx4 v0 = *(const floatx4*)vr;
            floatx4 v1 = *(const floatx4*)(vr + 4);
#pragma unroll
            for (int i = 0; i < 4; ++i) {
                Vt[(sdg * 8 + i) * 32 + skey] = (bf16_t)v0[i];
                Vt[(sdg * 8 + 4 + i) * 32 + skey] = (bf16_t)v1[i];
            }
        }
        __syncthreads();

        if (j0 <= qimax) {
            // S = Q K^T  (two 16x16 key sub-tiles)
            floatx4 sc[2];
#pragma unroll
            for (int jt = 0; jt < 2; ++jt) {
                bf16x8 bk0 = *(const bf16x8*)&Ks[0][(jt * 16 + l16) * 32 + quad * 8];
                bf16x8 bk1 = *(const bf16x8*)&Ks[1][(jt * 16 + l16) * 32 + quad * 8];
                floatx4 z = {0.f, 0.f, 0.f, 0.f};
                z = __builtin_amdgcn_mfma_f32_16x16x32_bf16(aq0, bk0, z, 0, 0, 0);
                z = __builtin_amdgcn_mfma_f32_16x16x32_bf16(aq1, bk1, z, 0, 0, 0);
                sc[jt] = z;
            }
            // online softmax per q-row (rows quad*4+r live in this lane)
#pragma unroll
            for (int r = 0; r < 4; ++r) {
                const int qi = t0 + wave * 16 + quad * 4 + r;
                float s0 = (j0 + l16 <= qi) ? sc[0][r] : -1e30f;
                float s1 = (j0 + 16 + l16 <= qi) ? sc[1][r] : -1e30f;
                float mx = fmaxf(s0, s1);
#pragma unroll
                for (int off = 1; off < 16; off <<= 1)
                    mx = fmaxf(mx, __shfl_xor(mx, off));
                const float mnew = fmaxf(mrow[r], mx);
                const float alpha = exp2f((mrow[r] - mnew) * c2);
                mrow[r] = mnew;
                const float p0 = exp2f((s0 - mnew) * c2);
                const float p1 = exp2f((s1 - mnew) * c2);
                float ps = p0 + p1;
#pragma unroll
                for (int off = 1; off < 16; off <<= 1)
                    ps += __shfl_xor(ps, off);
                lrow[r] = lrow[r] * alpha + ps;
#pragma unroll
                for (int nt = 0; nt < 4; ++nt) o[nt][r] *= alpha;
                Ps[wave][(quad * 4 + r) * 32 + l16] = (bf16_t)p0;
                Ps[wave][(quad * 4 + r) * 32 + 16 + l16] = (bf16_t)p1;
            }
            asm volatile("s_waitcnt lgkmcnt(0)" ::: "memory");  // wave-local write->read
            bf16x8 ap = *(const bf16x8*)&Ps[wave][l16 * 32 + quad * 8];
#pragma unroll
            for (int nt = 0; nt < 4; ++nt) {
                bf16x8 bv = *(const bf16x8*)&Vt[(nt * 16 + l16) * 32 + quad * 8];
                o[nt] = __builtin_amdgcn_mfma_f32_16x16x32_bf16(ap, bv, o[nt], 0, 0, 0);
            }
        }
        __syncthreads();
    }

    // epilogue: ao[(b*S + s)*D + h*64 + d]
#pragma unroll
    for (int r = 0; r < 4; ++r) {
        const float inv = 1.0f / lrow[r];
        const int s = t0 + wave * 16 + quad * 4 + r;
        bf16_t* dst = ao + ((size_t)(b * SS + s) * DD) + h * DH;
#pragma unroll
        for (int nt = 0; nt < 4; ++nt)
            dst[nt * 16 + l16] = (bf16_t)(o[nt][r] * inv);
    }
}

// ---------------------------------------------------------------------------
extern "C" void kernel_launch(void* const* d_in, const int* in_sizes, int n_in,
                              void* d_out, int out_size, void* d_ws, size_t ws_size,
                              hipStream_t stream) {
    // Select inputs BY SIZE (ordering-proof).
    const void* x_raw = nullptr;      // 8388608
    const void* w_in_raw = nullptr;   // 3145728
    const void* b_in_raw = nullptr;   // 3072
    const void* w_out_raw = nullptr;  // 1048576
    const void* b_out_raw = nullptr;  // 1024
    for (int i = 0; i < n_in; ++i) {
        switch (in_sizes[i]) {
            case 8388608: x_raw = d_in[i]; break;
            case 3145728: w_in_raw = d_in[i]; break;
            case 3072:    b_in_raw = d_in[i]; break;
            case 1048576: w_out_raw = d_in[i]; break;
            case 1024:    b_out_raw = d_in[i]; break;
            default: break;
        }
    }

    // d_out is FP32: out [4,2048,1024] | k [4,16,2048,64] | v [4,16,2048,64]
    float* outf  = (float*)d_out;
    float* koutf = outf + (size_t)MM * DD;
    float* voutf = koutf + (size_t)MM * DD;

    // q bf16 scratch lives in the out-section (16.8 MB of its 33.5 MB);
    // dead before the final GEMM overwrites the section.
    bf16_t* q_ws = (bf16_t*)d_out;

    char* ws = (char*)d_ws;                                  // ~25.2 MB used
    int*    flag    = (int*)ws;                              // 256 B
    bf16_t* xc      = (bf16_t*)(ws + 256);                   // [8192,1024]  16.78 MB
    bf16_t* ao_ws   = xc;                                    // alias: xc dead after gemm0
    bf16_t* w_in_t  = (bf16_t*)(ws + 16777472);              // [3072,1024]   6.29 MB
    bf16_t* w_out_t = (bf16_t*)(ws + 23068928);              // [1024,1024]   2.10 MB
    bf16_t* b_in_c  = (bf16_t*)(ws + 25166080);              // [3072]
    bf16_t* b_out_c = (bf16_t*)(ws + 25172224);              // [1024]

    detect_dtype<<<1, 64, 0, stream>>>((const unsigned short*)x_raw, flag);

    convert_x<<<(MM * DD / 4 + 255) / 256, 256, 0, stream>>>(x_raw, xc, flag, MM * DD);
    transpose_cvt<<<dim3(3 * DD / 32, DD / 32), 256, 0, stream>>>(w_in_raw, w_in_t, flag, DD, 3 * DD);
    transpose_cvt<<<dim3(DD / 32, DD / 32), 256, 0, stream>>>(w_out_raw, w_out_t, flag, DD, DD);
    convert1d<<<(3 * DD + 255) / 256, 256, 0, stream>>>(b_in_raw, b_in_c, flag, 3 * DD);
    convert1d<<<(DD + 255) / 256, 256, 0, stream>>>(b_out_raw, b_out_c, flag, DD);

    // qkv = x @ w_in + b_in; q -> bf16 scratch, k/v -> fp32 output sections
    gemm128<0><<<dim3(3 * DD / 128, MM / 128), 256, 0, stream>>>(
        xc, w_in_t, b_in_c, q_ws, koutf, voutf, nullptr, DD, 3 * DD);

    // causal flash attention -> ao [B,S,D] bf16 (in ws)
    flash64<<<dim3(SS / 64, BB * HH), 256, 0, stream>>>(q_ws, koutf, voutf, ao_ws);

    // out = ao @ w_out + b_out -> fp32 out section (overwrites q scratch)
    gemm128<1><<<dim3(DD / 128, MM / 128), 256, 0, stream>>>(
        ao_ws, w_out_t, b_out_c, nullptr, nullptr, nullptr, outf, DD, DD);
}

// Round 6
// 606.427 us; speedup vs baseline: 1.0497x; 1.0497x over previous
//
#include <hip/hip_runtime.h>
#include <hip/hip_bf16.h>
#include <math.h>

typedef __bf16 bf16_t;
typedef __bf16 bf16x2 __attribute__((ext_vector_type(2)));
typedef __bf16 bf16x4 __attribute__((ext_vector_type(4)));
typedef __bf16 bf16x8 __attribute__((ext_vector_type(8)));
typedef float floatx4 __attribute__((ext_vector_type(4)));
typedef unsigned short ushort4v __attribute__((ext_vector_type(4)));

#define AS1 __attribute__((address_space(1)))
#define AS3 __attribute__((address_space(3)))

// Problem constants
#define BB 4
#define SS 2048
#define DD 1024
#define HH 16
#define DH 64
#define MM (BB * SS)          // 8192

__device__ __forceinline__ void gld_lds16(const bf16_t* g, bf16_t* l) {
    __builtin_amdgcn_global_load_lds((const AS1 void*)g, (AS3 void*)l, 16, 0, 0);
}

// ---------------------------------------------------------------------------
// dtype detector (flag=1 -> fp32 inputs)
// ---------------------------------------------------------------------------
__global__ void detect_dtype(const unsigned short* __restrict__ x, int* __restrict__ flag) {
    if (threadIdx.x == 0) {
        int hits = 0;
        for (int i = 0; i < 128; ++i) {
            int e = (x[i] >> 7) & 0xFF;
            if (e >= 144) ++hits;
        }
        *flag = (hits >= 4) ? 1 : 0;
    }
}

__global__ __launch_bounds__(256)
void convert_x(const void* __restrict__ in, bf16_t* __restrict__ out,
               const int* __restrict__ flag, int n) {
    const int i4 = (blockIdx.x * 256 + threadIdx.x) * 4;
    if (i4 >= n) return;
    if (*flag) {
        floatx4 v = ((const floatx4*)in)[i4 >> 2];
        out[i4 + 0] = (bf16_t)v[0];
        out[i4 + 1] = (bf16_t)v[1];
        out[i4 + 2] = (bf16_t)v[2];
        out[i4 + 3] = (bf16_t)v[3];
    } else {
        ((ushort4v*)out)[i4 >> 2] = ((const ushort4v*)in)[i4 >> 2];
    }
}

__global__ void convert1d(const void* __restrict__ in, bf16_t* __restrict__ out,
                          const int* __restrict__ flag, int n) {
    const int i = blockIdx.x * 256 + threadIdx.x;
    if (i >= n) return;
    out[i] = (*flag) ? (bf16_t)((const float*)in)[i] : ((const bf16_t*)in)[i];
}

__global__ void transpose_cvt(const void* __restrict__ in, bf16_t* __restrict__ out,
                              const int* __restrict__ flag, int R, int C) {
    __shared__ bf16_t tile[32][33];
    const int tx = threadIdx.x & 31;
    const int ty = threadIdx.x >> 5;
    const int r0 = blockIdx.y * 32;
    const int c0 = blockIdx.x * 32;
    if (*flag) {
        const float* fin = (const float*)in;
#pragma unroll
        for (int i = 0; i < 32; i += 8)
            tile[ty + i][tx] = (bf16_t)fin[(size_t)(r0 + ty + i) * C + (c0 + tx)];
    } else {
        const bf16_t* bin = (const bf16_t*)in;
#pragma unroll
        for (int i = 0; i < 32; i += 8)
            tile[ty + i][tx] = bin[(size_t)(r0 + ty + i) * C + (c0 + tx)];
    }
    __syncthreads();
#pragma unroll
    for (int i = 0; i < 32; i += 8)
        out[(size_t)(c0 + ty + i) * R + (r0 + tx)] = tile[tx][ty + i];
}

// ---------------------------------------------------------------------------
// v_t [B*H*DH][SS] bf16  ->  vout [B*H][SS][DH] fp32  (tiled transpose)
// grid (S/32, 2, B*H), 256 threads (32x8)
// ---------------------------------------------------------------------------
__global__ __launch_bounds__(256)
void vexpand(const bf16_t* __restrict__ vt, float* __restrict__ vout) {
    __shared__ float tile[32][33];
    const int tx = threadIdx.x & 31;
    const int ty = threadIdx.x >> 5;
    const int s0 = blockIdx.x * 32;
    const int d0 = blockIdx.y * 32;
    const int bh = blockIdx.z;
#pragma unroll
    for (int i = 0; i < 32; i += 8)
        tile[ty + i][tx] = (float)vt[(size_t)(bh * DH + d0 + ty + i) * SS + s0 + tx];
    __syncthreads();
#pragma unroll
    for (int i = 0; i < 32; i += 8)
        vout[((size_t)bh * SS + s0 + ty + i) * DH + d0 + tx] = tile[tx][ty + i];
}

// ---------------------------------------------------------------------------
// 128x128 bf16 MFMA GEMM, A[M,K] row-major, Bt[N,K] row-major.
// MODE 0: qkv epilogue: q -> bf16 [bh][s][64]; k -> fp32 [bh][s][64] AND
//         bf16 k_bf [bh][s][64]; v -> bf16 v_t [bh*64+d][s] (packed b64).
// MODE 1: plain fp32 out.
// ---------------------------------------------------------------------------
template <int MODE>
__global__ __launch_bounds__(256)
void gemm128(const bf16_t* __restrict__ A, const bf16_t* __restrict__ Bt,
             const bf16_t* __restrict__ bias,
             bf16_t* __restrict__ qout, float* __restrict__ kf,
             bf16_t* __restrict__ kb, bf16_t* __restrict__ vtp,
             float* __restrict__ outf,
             int K, int N) {
    __shared__ bf16_t As[128 * 32];
    __shared__ bf16_t Bs[128 * 32];
    const int tid = threadIdx.x;
    const int wave = tid >> 6;
    const int lane = tid & 63;
    const int quad = lane >> 4;
    const int l16 = lane & 15;
    const int m0 = blockIdx.y * 128;
    const int n0 = blockIdx.x * 128;
    const int wm = (wave & 1) * 64;
    const int wn = (wave >> 1) * 64;

    floatx4 acc[4][4];
#pragma unroll
    for (int i = 0; i < 4; ++i)
#pragma unroll
        for (int j = 0; j < 4; ++j) {
            floatx4 z = {0.f, 0.f, 0.f, 0.f};
            acc[i][j] = z;
        }

    const int srow = wave * 32 + (lane >> 2);
    const int scol = (lane & 3) * 8;
    const bf16_t* ag = A + (size_t)(m0 + srow) * K + scol;
    const bf16_t* bg = Bt + (size_t)(n0 + srow) * K + scol;
    bf16_t* al = As + (wave * 32) * 32;
    bf16_t* bl = Bs + (wave * 32) * 32;

    for (int k0 = 0; k0 < K; k0 += 32) {
        gld_lds16(ag + k0, al);
        gld_lds16(ag + (size_t)16 * K + k0, al + 16 * 32);
        gld_lds16(bg + k0, bl);
        gld_lds16(bg + (size_t)16 * K + k0, bl + 16 * 32);
        __syncthreads();

        bf16x8 af[4], bfv[4];
#pragma unroll
        for (int mt = 0; mt < 4; ++mt)
            af[mt] = *(const bf16x8*)&As[(wm + mt * 16 + l16) * 32 + quad * 8];
#pragma unroll
        for (int nt = 0; nt < 4; ++nt)
            bfv[nt] = *(const bf16x8*)&Bs[(wn + nt * 16 + l16) * 32 + quad * 8];
#pragma unroll
        for (int mt = 0; mt < 4; ++mt)
#pragma unroll
            for (int nt = 0; nt < 4; ++nt)
                acc[mt][nt] = __builtin_amdgcn_mfma_f32_16x16x32_bf16(
                    af[mt], bfv[nt], acc[mt][nt], 0, 0, 0);
        __syncthreads();
    }

    // C row = wm+mt*16+quad*4+r, col = wn+nt*16+l16
#pragma unroll
    for (int mt = 0; mt < 4; ++mt) {
#pragma unroll
        for (int nt = 0; nt < 4; ++nt) {
            const int nc = n0 + wn + nt * 16 + l16;
            const float bv = (float)bias[nc];
            if (MODE == 0) {
                const int sec = nc >> 10;       // 0=q 1=k 2=v
                const int c = nc & 1023;
                const int h = c >> 6;
                const int dcol = c & 63;
                const int mb = m0 + wm + mt * 16 + quad * 4;   // 4-aligned, within one b
                const int b = mb >> 11;
                const int sbase = mb & 2047;
                if (sec == 2) {
                    // v_t[bh*64+dcol][s]: 4 consecutive s -> one b64 store
                    bf16x4 pk;
#pragma unroll
                    for (int r = 0; r < 4; ++r) pk[r] = (bf16_t)(acc[mt][nt][r] + bv);
                    *(bf16x4*)&vtp[((size_t)(b * HH + h) * DH + dcol) * SS + sbase] = pk;
                } else {
#pragma unroll
                    for (int r = 0; r < 4; ++r) {
                        const size_t di = ((size_t)(b * HH + h) * SS + sbase + r) * DH + dcol;
                        const float val = acc[mt][nt][r] + bv;
                        if (sec == 0) {
                            qout[di] = (bf16_t)val;
                        } else {
                            kf[di] = val;
                            kb[di] = (bf16_t)val;
                        }
                    }
                }
            } else {
#pragma unroll
                for (int r = 0; r < 4; ++r) {
                    const int m = m0 + wm + mt * 16 + quad * 4 + r;
                    outf[(size_t)m * N + nc] = acc[mt][nt][r] + bv;
                }
            }
        }
    }
}

// ---------------------------------------------------------------------------
// Causal flash attention v2: ONE WAVE PER BLOCK (64 thr), 16 q-rows/wave,
// 64-key tiles, zero barriers, zero K/V LDS staging — all MFMA operands are
// direct global b128 loads (k_bf [bh][s][64], v_t [bh*64+d][s], q [bh][s][64]).
// Lane<->key swizzle: score col l16 of sub-tile (ch,par) = key j0+32ch+2*l16+par
// -> P pairs are consecutive keys -> single packed ds_write_b32; Ps column
// order comes out natural so V-frags read v_t in natural key order.
// grid (S/16, B*H) with st reversed for longest-first dispatch.
// ---------------------------------------------------------------------------
__global__ __launch_bounds__(64)
void flash_v2(const bf16_t* __restrict__ q, const bf16_t* __restrict__ kbf,
              const bf16_t* __restrict__ vt, bf16_t* __restrict__ ao) {
#define PST 72   // Ps row stride (64 + 8 pad) -> conflict-light
    __shared__ bf16_t Ps[16 * PST];
    const int lane = threadIdx.x;
    const int quad = lane >> 4;
    const int l16 = lane & 15;
    const int st = (int)gridDim.x - 1 - (int)blockIdx.x;   // longest blocks first
    const int bh = blockIdx.y;
    const int b = bh >> 4;
    const int h = bh & 15;
    const int r0 = st * 16;

    const bf16_t* qp = q + (size_t)bh * SS * DH;
    const bf16_t* kp = kbf + (size_t)bh * SS * DH;
    const bf16_t* vp = vt + (size_t)bh * DH * SS;

    // Q A-frags: A[m=l16][k=quad*8+j]
    bf16x8 aq0, aq1;
    {
        const bf16_t* qr = qp + (size_t)(r0 + l16) * DH + quad * 8;
        aq0 = *(const bf16x8*)qr;
        aq1 = *(const bf16x8*)(qr + 32);
    }

    floatx4 o[4];
#pragma unroll
    for (int nt = 0; nt < 4; ++nt) {
        floatx4 z = {0.f, 0.f, 0.f, 0.f};
        o[nt] = z;
    }
    float mrow[4], lrow[4];
#pragma unroll
    for (int r = 0; r < 4; ++r) { mrow[r] = -1e30f; lrow[r] = 0.f; }

    const float c2 = 0.18033688011112042f;   // (1/sqrt(64)) * log2(e)
    const int kend = r0 + 16;

    for (int j0 = 0; j0 < kend; j0 += 64) {
        // ---- scores: 4 sub-tiles (ch,par), swizzled keys ----
        floatx4 sc[4];
        int key[4];
#pragma unroll
        for (int cp = 0; cp < 4; ++cp) {
            key[cp] = j0 + (cp >> 1) * 32 + 2 * l16 + (cp & 1);
            const bf16_t* kr = kp + (size_t)key[cp] * DH;
            bf16x8 bk0 = *(const bf16x8*)(kr + quad * 8);
            bf16x8 bk1 = *(const bf16x8*)(kr + 32 + quad * 8);
            floatx4 z = {0.f, 0.f, 0.f, 0.f};
            z = __builtin_amdgcn_mfma_f32_16x16x32_bf16(aq0, bk0, z, 0, 0, 0);
            z = __builtin_amdgcn_mfma_f32_16x16x32_bf16(aq1, bk1, z, 0, 0, 0);
            sc[cp] = z;
        }
        // ---- online softmax (rows quad*4+r) ----
#pragma unroll
        for (int r = 0; r < 4; ++r) {
            const int qi = r0 + quad * 4 + r;
            float s[4];
#pragma unroll
            for (int cp = 0; cp < 4; ++cp)
                s[cp] = (key[cp] <= qi) ? sc[cp][r] : -1e30f;
            float mx = fmaxf(fmaxf(s[0], s[1]), fmaxf(s[2], s[3]));
#pragma unroll
            for (int off = 1; off < 16; off <<= 1)
                mx = fmaxf(mx, __shfl_xor(mx, off));
            const float mnew = fmaxf(mrow[r], mx);
            const float alpha = exp2f((mrow[r] - mnew) * c2);
            mrow[r] = mnew;
            float p[4];
#pragma unroll
            for (int cp = 0; cp < 4; ++cp)
                p[cp] = exp2f((s[cp] - mnew) * c2);
            float ps = (p[0] + p[1]) + (p[2] + p[3]);
#pragma unroll
            for (int off = 1; off < 16; off <<= 1)
                ps += __shfl_xor(ps, off);
            lrow[r] = lrow[r] * alpha + ps;
#pragma unroll
            for (int nt = 0; nt < 4; ++nt) o[nt][r] *= alpha;
            const int qrow = quad * 4 + r;
            bf16x2 w0, w1;
            w0[0] = (bf16_t)p[0]; w0[1] = (bf16_t)p[1];
            w1[0] = (bf16_t)p[2]; w1[1] = (bf16_t)p[3];
            *(bf16x2*)&Ps[qrow * PST + 2 * l16] = w0;        // keys j0 + 2*l16+{0,1}
            *(bf16x2*)&Ps[qrow * PST + 32 + 2 * l16] = w1;   // keys j0+32+2*l16+{0,1}
        }
        asm volatile("s_waitcnt lgkmcnt(0)" ::: "memory");   // wave-local write->read
        // ---- PV: A-frags from Ps (natural key order), B-frags from v_t ----
        bf16x8 ap0 = *(const bf16x8*)&Ps[l16 * PST + quad * 8];
        bf16x8 ap1 = *(const bf16x8*)&Ps[l16 * PST + 32 + quad * 8];
#pragma unroll
        for (int nt = 0; nt < 4; ++nt) {
            const bf16_t* vr = vp + (size_t)(nt * 16 + l16) * SS + j0;
            bf16x8 bv0 = *(const bf16x8*)(vr + quad * 8);
            bf16x8 bv1 = *(const bf16x8*)(vr + 32 + quad * 8);
            o[nt] = __builtin_amdgcn_mfma_f32_16x16x32_bf16(ap0, bv0, o[nt], 0, 0, 0);
            o[nt] = __builtin_amdgcn_mfma_f32_16x16x32_bf16(ap1, bv1, o[nt], 0, 0, 0);
        }
    }

    // epilogue: ao[(b*S + s)*D + h*64 + d]
#pragma unroll
    for (int r = 0; r < 4; ++r) {
        const float inv = 1.0f / lrow[r];
        const int s = r0 + quad * 4 + r;
        bf16_t* dst = ao + ((size_t)(b * SS + s) * DD) + h * DH;
#pragma unroll
        for (int nt = 0; nt < 4; ++nt)
            dst[nt * 16 + l16] = (bf16_t)(o[nt][r] * inv);
    }
#undef PST
}

// ---------------------------------------------------------------------------
extern "C" void kernel_launch(void* const* d_in, const int* in_sizes, int n_in,
                              void* d_out, int out_size, void* d_ws, size_t ws_size,
                              hipStream_t stream) {
    // Select inputs BY SIZE (ordering-proof).
    const void* x_raw = nullptr;      // 8388608
    const void* w_in_raw = nullptr;   // 3145728
    const void* b_in_raw = nullptr;   // 3072
    const void* w_out_raw = nullptr;  // 1048576
    const void* b_out_raw = nullptr;  // 1024
    for (int i = 0; i < n_in; ++i) {
        switch (in_sizes[i]) {
            case 8388608: x_raw = d_in[i]; break;
            case 3145728: w_in_raw = d_in[i]; break;
            case 3072:    b_in_raw = d_in[i]; break;
            case 1048576: w_out_raw = d_in[i]; break;
            case 1024:    b_out_raw = d_in[i]; break;
            default: break;
        }
    }

    // d_out (fp32): out [4,2048,1024] | k [4,16,2048,64] | v [4,16,2048,64]
    float* outf  = (float*)d_out;
    float* koutf = outf + (size_t)MM * DD;
    float* voutf = koutf + (size_t)MM * DD;

    // bf16 scratch inside the fp32 out-section (33.55 MB):
    //   lower half: q [bh][s][64]   (16.78 MB)
    //   upper half: k_bf [bh][s][64] (16.78 MB)
    // both dead before the final GEMM overwrites the section.
    bf16_t* q_ws = (bf16_t*)d_out;
    bf16_t* k_bf = q_ws + (size_t)MM * DD;

    char* ws = (char*)d_ws;                                  // ~42 MB used (proven >= 42 MB)
    int*    flag    = (int*)ws;                              // 256 B
    bf16_t* xc      = (bf16_t*)(ws + 256);                   // [8192,1024]  16.78 MB
    bf16_t* ao_ws   = xc;                                    // alias: xc dead after gemm0
    bf16_t* w_in_t  = (bf16_t*)(ws + 16777472);              // [3072,1024]   6.29 MB
    bf16_t* w_out_t = (bf16_t*)(ws + 23068928);              // [1024,1024]   2.10 MB
    bf16_t* b_in_c  = (bf16_t*)(ws + 25166080);              // [3072]
    bf16_t* b_out_c = (bf16_t*)(ws + 25172224);              // [1024]
    bf16_t* v_t     = (bf16_t*)(ws + 25174272);              // [bh*64][2048] 16.78 MB

    detect_dtype<<<1, 64, 0, stream>>>((const unsigned short*)x_raw, flag);

    convert_x<<<(MM * DD / 4 + 255) / 256, 256, 0, stream>>>(x_raw, xc, flag, MM * DD);
    transpose_cvt<<<dim3(3 * DD / 32, DD / 32), 256, 0, stream>>>(w_in_raw, w_in_t, flag, DD, 3 * DD);
    transpose_cvt<<<dim3(DD / 32, DD / 32), 256, 0, stream>>>(w_out_raw, w_out_t, flag, DD, DD);
    convert1d<<<(3 * DD + 255) / 256, 256, 0, stream>>>(b_in_raw, b_in_c, flag, 3 * DD);
    convert1d<<<(DD + 255) / 256, 256, 0, stream>>>(b_out_raw, b_out_c, flag, DD);

    // qkv = x @ w_in + b_in
    gemm128<0><<<dim3(3 * DD / 128, MM / 128), 256, 0, stream>>>(
        xc, w_in_t, b_in_c, q_ws, koutf, k_bf, v_t, nullptr, DD, 3 * DD);

    // v fp32 output from v_t
    vexpand<<<dim3(SS / 32, DH / 32, BB * HH), 256, 0, stream>>>(v_t, voutf);

    // causal flash attention -> ao (bf16, in ws)
    flash_v2<<<dim3(SS / 16, BB * HH), 64, 0, stream>>>(q_ws, k_bf, v_t, ao_ws);

    // out = ao @ w_out + b_out (overwrites q/k_bf scratch)
    gemm128<1><<<dim3(DD / 128, MM / 128), 256, 0, stream>>>(
        ao_ws, w_out_t, b_out_c, nullptr, nullptr, nullptr, nullptr, outf, DD, DD);
}